// Round 12
// baseline (176.525 us; speedup 1.0000x reference)
//
#include <hip/hip_runtime.h>
#include <hip/hip_bf16.h>
#include <stdint.h>

typedef __bf16 bf16x8 __attribute__((ext_vector_type(8)));
typedef float  f32x16 __attribute__((ext_vector_type(16)));

#define K2EXP 7.2134752044448170f   /* log2(e)/T */
#define LN2F  0.6931471805599453f

__device__ __forceinline__ unsigned short f2bf(float f) {
  __bf16 h = (__bf16)f;
  return __builtin_bit_cast(unsigned short, h);
}

// gt: row-normalized g_enc as bf16, TRANSPOSED for coalesced B-fragment
// loads: 16B unit (s, col, lh) holds elements k = s*16+lh*8 .. +8 of graph
// column `col`, at byte offset s*32768 + col*32 + lh*16.  (512 KB total)
__global__ __launch_bounds__(256) void k_ghat(const float* __restrict__ g,
                                              char* __restrict__ gt) {
  const int w = threadIdx.x >> 6, l = threadIdx.x & 63;
  const int row = blockIdx.x * 4 + w;       // one graph row per wave
  const float4 v = *(const float4*)(g + (size_t)row * 256 + l * 4);
  float s = v.x * v.x + v.y * v.y + v.z * v.z + v.w * v.w;
  #pragma unroll
  for (int m = 1; m <= 32; m <<= 1) s += __shfl_xor(s, m, 64);
  const float rn = rsqrtf(s);
  ushort4 o;
  o.x = f2bf(v.x * rn); o.y = f2bf(v.y * rn);
  o.z = f2bf(v.z * rn); o.w = f2bf(v.w * rn);
  const unsigned long long pk = __builtin_bit_cast(unsigned long long, o);
  // unit j (=lane, j<32) needs k=8j..8j+7 -> lanes 2j (lo) and 2j+1 (hi)
  const unsigned long long lo = __shfl(pk, (l & 31) * 2, 64);
  const unsigned long long hi = __shfl(pk, (l & 31) * 2 + 1, 64);
  if (l < 32) {
    char* dst = gt + (l >> 1) * 32768 + row * 32 + (l & 1) * 16;
    ((unsigned long long*)dst)[0] = lo;
    ((unsigned long long*)dst)[1] = hi;
  }
}

// Main fused kernel, barrier-free K-loop: 4 waves/block, 32 rows/wave,
// A-panel in 16 named bf16x8 regs; B read DIRECTLY from global (L2/L3-
// resident 512 KB, coalesced 1KB loads via the transposed gt layout).
// No LDS staging, no __syncthreads in the loop -> occupancy is VGPR-bound
// and latency is hidden by TLP instead of pipelining heroics.
__global__ __launch_bounds__(256)
__attribute__((amdgpu_waves_per_eu(2)))
void k_main(const float* __restrict__ l2,
            const char* __restrict__ gt,
            float* __restrict__ out) {
  __shared__ float posl[128];
  __shared__ float bsum;

  const int tid = threadIdx.x;
  const int w   = tid >> 6;      // 0..3
  const int l   = tid & 63;
  const int lm  = l & 31;
  const int lh  = l >> 5;
  const int wrb = blockIdx.x * 128 + w * 32;  // wave's first row
  const int p   = blockIdx.x;    // positive column (block-uniform: 128 rows)
  const int pcf = p >> 5;        // 32-col fragment containing p
  const int plm = p & 31;

  if (tid == 0) bsum = 0.f;

  // A load + pack + sum-of-squares, single HBM pass. afS: row wrb+lm,
  // k = S*16 + lh*8 .. +8. Named registers.
  bf16x8 af0, af1, af2, af3, af4, af5, af6, af7,
         af8, af9, af10, af11, af12, af13, af14, af15;
  float ssq = 0.f;
  const float* rp = l2 + (size_t)(wrb + lm) * 256 + lh * 8;

#define LOADA(s) { \
    const float4 a = *(const float4*)(rp + (s) * 16); \
    const float4 b = *(const float4*)(rp + (s) * 16 + 4); \
    ssq += a.x*a.x + a.y*a.y + a.z*a.z + a.w*a.w \
         + b.x*b.x + b.y*b.y + b.z*b.z + b.w*b.w; \
    bf16x8 f; \
    f[0] = (__bf16)a.x; f[1] = (__bf16)a.y; f[2] = (__bf16)a.z; f[3] = (__bf16)a.w; \
    f[4] = (__bf16)b.x; f[5] = (__bf16)b.y; f[6] = (__bf16)b.z; f[7] = (__bf16)b.w; \
    af##s = f; }

  LOADA(0) LOADA(1) LOADA(2) LOADA(3)
  __builtin_amdgcn_sched_barrier(0);   // cap in-flight float4s
  LOADA(4) LOADA(5) LOADA(6) LOADA(7)
  __builtin_amdgcn_sched_barrier(0);
  LOADA(8) LOADA(9) LOADA(10) LOADA(11)
  __builtin_amdgcn_sched_barrier(0);
  LOADA(12) LOADA(13) LOADA(14) LOADA(15)
#undef LOADA

  // fold 1/||row|| into af in-register
  const float rn = rsqrtf(ssq + __shfl_xor(ssq, 32, 64));
#define NRM(s) { bf16x8 f = af##s; \
    f[0] = (__bf16)((float)f[0] * rn); f[1] = (__bf16)((float)f[1] * rn); \
    f[2] = (__bf16)((float)f[2] * rn); f[3] = (__bf16)((float)f[3] * rn); \
    f[4] = (__bf16)((float)f[4] * rn); f[5] = (__bf16)((float)f[5] * rn); \
    f[6] = (__bf16)((float)f[6] * rn); f[7] = (__bf16)((float)f[7] * rn); \
    af##s = f; }
  NRM(0) NRM(1) NRM(2) NRM(3) NRM(4) NRM(5) NRM(6) NRM(7)
  NRM(8) NRM(9) NRM(10) NRM(11) NRM(12) NRM(13) NRM(14) NRM(15)
#undef NRM

  float rs0 = 0.f, rs1 = 0.f, rs2 = 0.f, rs3 = 0.f,
        rs4 = 0.f, rs5 = 0.f, rs6 = 0.f, rs7 = 0.f,
        rs8 = 0.f, rs9 = 0.f, rs10 = 0.f, rs11 = 0.f,
        rs12 = 0.f, rs13 = 0.f, rs14 = 0.f, rs15 = 0.f;

  __syncthreads();   // bsum init visible; waves start K-loop together (L1 reuse)

#define MSTEP(s) { \
    const uint4 raw = *(const uint4*)(bp + (s) * 32768); \
    acc = __builtin_amdgcn_mfma_f32_32x32x16_bf16( \
              af##s, __builtin_bit_cast(bf16x8, raw), acc, 0, 0, 0); }
#define ESTEP(j) rs##j += __builtin_amdgcn_exp2f(acc[j] * K2EXP);

  for (int cf = 0; cf < 32; ++cf) {
    // lane reads col = cf*32+lm, k-slice (s, lh): contiguous 1KB per load
    const char* bp = gt + (size_t)((cf * 32 + lm) * 32 + lh * 16);
    f32x16 acc = {0.f};
    MSTEP(0)  MSTEP(1)  MSTEP(2)  MSTEP(3)
    MSTEP(4)  MSTEP(5)  MSTEP(6)  MSTEP(7)
    __builtin_amdgcn_sched_barrier(0);   // cap hoisted B-loads (~8 in flight)
    MSTEP(8)  MSTEP(9)  MSTEP(10) MSTEP(11)
    MSTEP(12) MSTEP(13) MSTEP(14) MSTEP(15)
    ESTEP(0)  ESTEP(1)  ESTEP(2)  ESTEP(3)
    ESTEP(4)  ESTEP(5)  ESTEP(6)  ESTEP(7)
    ESTEP(8)  ESTEP(9)  ESTEP(10) ESTEP(11)
    ESTEP(12) ESTEP(13) ESTEP(14) ESTEP(15)
    if (cf == pcf && lm == plm) {
      #pragma unroll
      for (int j = 0; j < 16; ++j) {
        const int r0 = (j & 3) + 8 * (j >> 2) + 4 * lh;
        posl[w * 32 + r0] = acc[j] * K2EXP;   // log2-scaled positive logit
      }
    }
  }
#undef MSTEP
#undef ESTEP

  // reduce row sums over the 32 column-lanes of each half-wave
#define RED(j) { float v = rs##j; \
    v += __shfl_xor(v, 1, 64); v += __shfl_xor(v, 2, 64); \
    v += __shfl_xor(v, 4, 64); v += __shfl_xor(v, 8, 64); \
    v += __shfl_xor(v, 16, 64); rs##j = v; }
  RED(0) RED(1) RED(2) RED(3) RED(4) RED(5) RED(6) RED(7)
  RED(8) RED(9) RED(10) RED(11) RED(12) RED(13) RED(14) RED(15)
#undef RED

  if (lm == 0) {  // lanes 0 and 32: 16 rows each
    float local = 0.f;
#define FIN(j) { \
    const int r0 = ((j) & 3) + 8 * ((j) >> 2) + 4 * lh; \
    const float cs = posl[w * 32 + r0]; \
    const float S  = rs##j - __builtin_amdgcn_exp2f(cs); \
    local += (__builtin_amdgcn_logf(S) - cs) * LN2F; }
    FIN(0) FIN(1) FIN(2) FIN(3) FIN(4) FIN(5) FIN(6) FIN(7)
    FIN(8) FIN(9) FIN(10) FIN(11) FIN(12) FIN(13) FIN(14) FIN(15)
#undef FIN
    atomicAdd(&bsum, local);
  }
  __syncthreads();
  if (tid == 0) atomicAdd(out, bsum * (1.0f / 131072.0f));
}

extern "C" void kernel_launch(void* const* d_in, const int* in_sizes, int n_in,
                              void* d_out, int out_size, void* d_ws, size_t ws_size,
                              hipStream_t stream) {
  (void)in_sizes; (void)n_in; (void)out_size; (void)ws_size;
  const float* l2 = (const float*)d_in[0];   // [131072, 256] fp32
  const float* g  = (const float*)d_in[1];   // [1024, 256] fp32
  float* out = (float*)d_out;

  char* gt = (char*)d_ws;                    // 512 KB bf16, transposed

  hipMemsetAsync(d_out, 0, sizeof(float), stream);
  k_ghat<<<256, 256, 0, stream>>>(g, gt);
  k_main<<<1024, 256, 0, stream>>>(l2, gt, out);
}

// Round 13
// 95.652 us; speedup vs baseline: 1.8455x; 1.8455x over previous
//
#include <hip/hip_runtime.h>
#include <hip/hip_bf16.h>
#include <stdint.h>

typedef __bf16 bf16x8 __attribute__((ext_vector_type(8)));
typedef float  f32x16 __attribute__((ext_vector_type(16)));

#define K2EXP 7.2134752044448170f   /* log2(e)/T */
#define LN2F  0.6931471805599453f

__device__ __forceinline__ unsigned short f2bf(float f) {
  __bf16 h = (__bf16)f;
  return __builtin_bit_cast(unsigned short, h);
}

// ghat: row-normalized g_enc as bf16, pre-swizzled: byte kb of row r lands at
// r*512 + (kb ^ ((r&31)<<4))  -- full 32-slot XOR permutation per 512B row.
__global__ __launch_bounds__(256) void k_ghat(const float* __restrict__ g,
                                              char* __restrict__ ghat) {
  const int w = threadIdx.x >> 6, l = threadIdx.x & 63;
  const int row = blockIdx.x * 4 + w;
  const float4 v = *(const float4*)(g + (size_t)row * 256 + l * 4);
  float s = v.x * v.x + v.y * v.y + v.z * v.z + v.w * v.w;
  #pragma unroll
  for (int m = 1; m <= 32; m <<= 1) s += __shfl_xor(s, m, 64);
  const float rn = rsqrtf(s);
  ushort4 o;
  o.x = f2bf(v.x * rn); o.y = f2bf(v.y * rn);
  o.z = f2bf(v.z * rn); o.w = f2bf(v.w * rn);
  const int off = row * 512 + ((l * 8) ^ ((row & 31) << 4));
  *(ushort4*)(ghat + off) = o;
}

// Main fused kernel, operand-SWAPPED: D[g][local] = mfma(A=g_frag, B=af).
// Each lane's acc[0..15] = 16 g-cols of ONE local row (col=lane&31), so the
// exp row-sum collapses into 4 registers and the epilogue is 2 shuffles +
// 1 log per lane (no posl LDS, no serial FIN chain). Per-wave state ~115
// unified regs -> waves_per_eu(3). B (g) double-buffered in 16KB LDS chunks.
__global__ __launch_bounds__(256)
__attribute__((amdgpu_waves_per_eu(3)))
void k_main(const float* __restrict__ l2,
            const char* __restrict__ ghat,
            float* __restrict__ out) {
  __shared__ __align__(16) char smem[2 * 16384 + 64];
  __shared__ float bsum;

  const int tid = threadIdx.x;
  const int w   = tid >> 6;      // 0..3
  const int l   = tid & 63;
  const int lm  = l & 31;
  const int lh  = l >> 5;
  const int wrb = blockIdx.x * 128 + w * 32;  // wave's first local row
  const int p   = blockIdx.x;    // positive g-col (block-uniform: 128 rows)
  const int pc  = p >> 5;        // 32-g chunk containing p
  const int pr  = p & 31;        // g-row within chunk
  const int lh_p = (pr >> 2) & 1;                 // acc half holding p
  const int j_p  = (pr & 3) | ((pr >> 3) << 2);   // acc reg holding p

  if (tid == 0) bsum = 0.f;

  // stage one 16KB chunk (32 g-rows) with 256 threads: 4 x 4KB segments
  auto stage = [&](int c, int buf) {
    const char* gsrc = ghat + c * 16384 + tid * 16;
    char* ldst = smem + buf * 16384 + w * 1024;   // + l*16 implicit in HW
    #pragma unroll
    for (int i = 0; i < 4; ++i) {
      __builtin_amdgcn_global_load_lds(
          (const __attribute__((address_space(1))) void*)(gsrc + i * 4096),
          (__attribute__((address_space(3))) void*)(ldst + i * 4096),
          16, 0, 0);
    }
  };

  stage(0, 0);  // fly under the A-load

  // Local-row panel (B operand): afS holds row wrb+lm, k = S*16 + lh*8 .. +8.
  // (B fragment layout: lane&31 = col j, lh = k-half -- same mapping as A.)
  bf16x8 af0, af1, af2, af3, af4, af5, af6, af7,
         af8, af9, af10, af11, af12, af13, af14, af15;
  float ssq = 0.f;
  const float* rp = l2 + (size_t)(wrb + lm) * 256 + lh * 8;

#define LOADA(s) { \
    const float4 a = *(const float4*)(rp + (s) * 16); \
    const float4 b = *(const float4*)(rp + (s) * 16 + 4); \
    ssq += a.x*a.x + a.y*a.y + a.z*a.z + a.w*a.w \
         + b.x*b.x + b.y*b.y + b.z*b.z + b.w*b.w; \
    bf16x8 f; \
    f[0] = (__bf16)a.x; f[1] = (__bf16)a.y; f[2] = (__bf16)a.z; f[3] = (__bf16)a.w; \
    f[4] = (__bf16)b.x; f[5] = (__bf16)b.y; f[6] = (__bf16)b.z; f[7] = (__bf16)b.w; \
    af##s = f; }

  LOADA(0) LOADA(1) LOADA(2) LOADA(3)
  __builtin_amdgcn_sched_barrier(0);   // cap in-flight float4s
  LOADA(4) LOADA(5) LOADA(6) LOADA(7)
  __builtin_amdgcn_sched_barrier(0);
  LOADA(8) LOADA(9) LOADA(10) LOADA(11)
  __builtin_amdgcn_sched_barrier(0);
  LOADA(12) LOADA(13) LOADA(14) LOADA(15)
#undef LOADA

  // fold 1/||row|| into af in-register
  const float rn = rsqrtf(ssq + __shfl_xor(ssq, 32, 64));
#define NRM(s) { bf16x8 f = af##s; \
    f[0] = (__bf16)((float)f[0] * rn); f[1] = (__bf16)((float)f[1] * rn); \
    f[2] = (__bf16)((float)f[2] * rn); f[3] = (__bf16)((float)f[3] * rn); \
    f[4] = (__bf16)((float)f[4] * rn); f[5] = (__bf16)((float)f[5] * rn); \
    f[6] = (__bf16)((float)f[6] * rn); f[7] = (__bf16)((float)f[7] * rn); \
    af##s = f; }
  NRM(0) NRM(1) NRM(2) NRM(3) NRM(4) NRM(5) NRM(6) NRM(7)
  NRM(8) NRM(9) NRM(10) NRM(11) NRM(12) NRM(13) NRM(14) NRM(15)
#undef NRM

  // 4 partial exp-sums (break the add dependency chain); cs = positive logit
  float rsa = 0.f, rsb = 0.f, rsc = 0.f, rsd = 0.f;
  float cs = 0.f;

  __syncthreads();  // buf0 staged (barrier drains vmcnt) + bsum init visible

  // A operand = g fragment from LDS: g-row lm of chunk, k-slice (s, lh).
#define MSTEP(s) { \
    const uint4 raw = *(const uint4*)(base + lm * 512 + (((s) * 32 + lh * 16) ^ sw)); \
    acc = __builtin_amdgcn_mfma_f32_32x32x16_bf16( \
              __builtin_bit_cast(bf16x8, raw), af##s, acc, 0, 0, 0); }

  const int sw = lm << 4;
  for (int c = 0; c < 32; ++c) {
    if (c < 31) stage(c + 1, (c + 1) & 1);   // issue next chunk FIRST
    const char* base = smem + (c & 1) * 16384;
    f32x16 acc = {0.f};
    MSTEP(0)  MSTEP(1)  MSTEP(2)  MSTEP(3)
    MSTEP(4)  MSTEP(5)  MSTEP(6)  MSTEP(7)
    MSTEP(8)  MSTEP(9)  MSTEP(10) MSTEP(11)
    MSTEP(12) MSTEP(13) MSTEP(14) MSTEP(15)
    rsa += __builtin_amdgcn_exp2f(acc[0] * K2EXP);
    rsb += __builtin_amdgcn_exp2f(acc[1] * K2EXP);
    rsc += __builtin_amdgcn_exp2f(acc[2] * K2EXP);
    rsd += __builtin_amdgcn_exp2f(acc[3] * K2EXP);
    rsa += __builtin_amdgcn_exp2f(acc[4] * K2EXP);
    rsb += __builtin_amdgcn_exp2f(acc[5] * K2EXP);
    rsc += __builtin_amdgcn_exp2f(acc[6] * K2EXP);
    rsd += __builtin_amdgcn_exp2f(acc[7] * K2EXP);
    rsa += __builtin_amdgcn_exp2f(acc[8] * K2EXP);
    rsb += __builtin_amdgcn_exp2f(acc[9] * K2EXP);
    rsc += __builtin_amdgcn_exp2f(acc[10] * K2EXP);
    rsd += __builtin_amdgcn_exp2f(acc[11] * K2EXP);
    rsa += __builtin_amdgcn_exp2f(acc[12] * K2EXP);
    rsb += __builtin_amdgcn_exp2f(acc[13] * K2EXP);
    rsc += __builtin_amdgcn_exp2f(acc[14] * K2EXP);
    rsd += __builtin_amdgcn_exp2f(acc[15] * K2EXP);
    if (c == pc) {
      // positive logit for local row lm sits in acc[j_p] on half lh_p
      #pragma unroll
      for (int j = 0; j < 16; ++j)
        if (j == j_p && lh == lh_p) cs = acc[j] * K2EXP;
    }
    __syncthreads();  // chunk c fully read; chunk c+1 staged
  }
#undef MSTEP

  // per-lane finish: rs over both k-halves, fetch cs from the half that has it
  float rs = (rsa + rsb) + (rsc + rsd);
  rs += __shfl_xor(rs, 32, 64);
  cs = __shfl(cs, lm | (lh_p << 5), 64);
  const float S = rs - __builtin_amdgcn_exp2f(cs);
  float term = (__builtin_amdgcn_logf(S) - cs) * LN2F;
  // sum over the 32 lanes of each half (halves are duplicates)
  term += __shfl_xor(term, 1, 64);  term += __shfl_xor(term, 2, 64);
  term += __shfl_xor(term, 4, 64);  term += __shfl_xor(term, 8, 64);
  term += __shfl_xor(term, 16, 64);
  if (l == 0) atomicAdd(&bsum, term);   // lane 0: wave's 32-row total
  __syncthreads();
  if (tid == 0) atomicAdd(out, bsum * (1.0f / 131072.0f));
}

extern "C" void kernel_launch(void* const* d_in, const int* in_sizes, int n_in,
                              void* d_out, int out_size, void* d_ws, size_t ws_size,
                              hipStream_t stream) {
  (void)in_sizes; (void)n_in; (void)out_size; (void)ws_size;
  const float* l2 = (const float*)d_in[0];   // [131072, 256] fp32
  const float* g  = (const float*)d_in[1];   // [1024, 256] fp32
  float* out = (float*)d_out;

  char* ghat = (char*)d_ws;                  // 512 KB bf16, swizzled

  hipMemsetAsync(d_out, 0, sizeof(float), stream);
  k_ghat<<<256, 256, 0, stream>>>(g, ghat);
  k_main<<<1024, 256, 0, stream>>>(l2, ghat, out);
}